// Round 4
// baseline (283.462 us; speedup 1.0000x reference)
//
#include <hip/hip_runtime.h>

#define C_ 256
#define N_ 4096
#define NH_ 8

typedef unsigned short u16;
typedef unsigned int u32;
typedef __attribute__((ext_vector_type(8))) short s8v;
typedef __attribute__((ext_vector_type(4))) float f4v;

#define MFMA16 __builtin_amdgcn_mfma_f32_16x16x32_bf16

__device__ __forceinline__ float bf2f(u16 b){ union{u32 u; float f;} v; v.u=((u32)b)<<16; return v.f; }
__device__ __forceinline__ u16 f2bf(float f){ union{float f; u32 u;} v; v.f=f; return (u16)((v.u + 0x7FFFu + ((v.u>>16)&1u))>>16); }

__device__ __forceinline__ void gl_lds16(const u16* g, u16* l){
  __builtin_amdgcn_global_load_lds((const __attribute__((address_space(1))) u32*)g,
                                   (__attribute__((address_space(3))) u32*)l, 16, 0, 0);
}

// ---------------- kernel A1: pixel rnorm + write xnT[b][n][c] bf16 ----------------
// 1024 blocks, 4 threads/pixel; x read once (held in regs), 256B-coalesced loads.
__global__ __launch_bounds__(256) void k_prep(const float* __restrict__ x, const float* __restrict__ nw,
                                              u16* __restrict__ xnT){
  __shared__ float red[256];
  __shared__ float nws[256];
  const int tid = threadIdx.x;
  nws[tid] = nw[tid];
  const int blk = blockIdx.x, b = blk>>6, n0 = (blk&63)*64;
  const int cq = tid>>6, px = tid&63;
  const float* xp = x + (size_t)b*(C_*N_) + (size_t)(cq*64)*N_ + n0 + px;
  float v[64]; float s = 0.f;
  #pragma unroll
  for (int i=0;i<64;i++){ float t = xp[(size_t)i*N_]; v[i]=t; s = fmaf(t,t,s); }
  red[tid] = s;
  __syncthreads();
  const float st = red[px] + red[64+px] + red[128+px] + red[192+px];
  const float r = 16.0f / fmaxf(sqrtf(st), 1e-12f);
  u16* o = xnT + ((size_t)b*4096 + n0 + px)*256 + cq*64;
  #pragma unroll
  for (int i=0;i<64;i+=2){
    *(u32*)(o+i) = (u32)f2bf(v[i]*r*nws[cq*64+i]) | ((u32)f2bf(v[i+1]*r*nws[cq*64+i+1])<<16);
  }
}

// ---------------- kernel A2: weights -> bf16 ----------------
__global__ __launch_bounds__(256) void k_wconv(const float* __restrict__ qkvw, const float* __restrict__ ow,
                                               u16* __restrict__ wqkv, u16* __restrict__ owb){
  int i = blockIdx.x*256 + threadIdx.x;   // 524288 total
  if (i < 393216) wqkv[i] = f2bf(qkvw[i]);
  else            owb[i-393216] = f2bf(ow[i-393216]);
}

// ---------------- kernel B: K/V GEMM + in-register flash softmax + ctx partials ----------------
// 1024 blocks (8ch x 8h x 16b, swizzled so same-(b,ch) h-blocks share an XCD), 4 waves.
// Tile = 64 pixels; softmax entirely in registers (shfl within 16-lane groups); 2 barriers/tile.
__global__ __launch_bounds__(256,4) void k_kv(const u16* __restrict__ xnT, const u16* __restrict__ wqkv,
    u16* __restrict__ ctxp, float* __restrict__ Mp, float* __restrict__ Sp){
  __shared__ u16 pbuf[64*72];
  __shared__ u16 vbuf[64*72];
  const int idx = blockIdx.x;
  const int h = idx>>7, b = (idx>>3)&15, ch = idx&7;   // idx%8==ch -> same (b,ch) group on one XCD
  const int tid=threadIdx.x, w=tid>>6, l=tid&63, l15=l&15, lg=l>>4;
  const u16* xb  = xnT + (size_t)b*(4096*256);
  const u16* wk0 = wqkv + (size_t)(512 + h*64 + w*16 + l15)*256 + lg*8;
  f4v acc[4];
  #pragma unroll
  for (int et=0;et<4;et++) acc[et] = (f4v){0.f,0.f,0.f,0.f};
  float M[4] = {-1e30f,-1e30f,-1e30f,-1e30f};
  float S[4] = {0.f,0.f,0.f,0.f};

  for (int t=0; t<8; ++t){
    const int n0 = ch*512 + t*64;
    f4v kacc[4], vacc[4];
    #pragma unroll
    for (int ns=0;ns<4;ns++){ kacc[ns]=(f4v){0.f,0.f,0.f,0.f}; vacc[ns]=(f4v){0.f,0.f,0.f,0.f}; }
    #pragma unroll
    for (int cs=0; cs<8; cs++){
      s8v ak = *(const s8v*)(wk0 + cs*32);
      s8v av = *(const s8v*)(wk0 + 131072 + cs*32);
      #pragma unroll
      for (int ns=0; ns<4; ns++){
        s8v bfr = *(const s8v*)(xb + (size_t)(n0 + ns*16 + l15)*256 + cs*32 + lg*8);
        kacc[ns] = MFMA16(ak, bfr, kacc[ns], 0,0,0);
        vacc[ns] = MFMA16(av, bfr, vacc[ns], 0,0,0);
      }
    }
    __syncthreads();   // prev tile's GEMM2 readers done
    #pragma unroll
    for (int j=0;j<4;j++){
      float mt = fmaxf(fmaxf(kacc[0][j],kacc[1][j]),fmaxf(kacc[2][j],kacc[3][j]));
      mt = fmaxf(mt, __shfl_xor(mt,1));
      mt = fmaxf(mt, __shfl_xor(mt,2));
      mt = fmaxf(mt, __shfl_xor(mt,4));
      mt = fmaxf(mt, __shfl_xor(mt,8));
      const float Mn = fmaxf(M[j], mt);
      const float f  = __expf(M[j]-Mn);
      const int row = w*16 + lg*4 + j;
      float ps = 0.f;
      #pragma unroll
      for (int ns=0;ns<4;ns++){
        float e = __expf(kacc[ns][j]-Mn);
        ps += e;
        pbuf[row*72 + ns*16+l15] = f2bf(e);
        vbuf[row*72 + ns*16+l15] = f2bf(vacc[ns][j]);
      }
      ps += __shfl_xor(ps,1); ps += __shfl_xor(ps,2);
      ps += __shfl_xor(ps,4); ps += __shfl_xor(ps,8);
      S[j] = S[j]*f + ps;
      M[j] = Mn;
      #pragma unroll
      for (int et=0;et<4;et++) acc[et][j] *= f;
    }
    __syncthreads();
    #pragma unroll
    for (int ks=0; ks<2; ks++){
      s8v af = *(const s8v*)(pbuf + (w*16+l15)*72 + ks*32 + lg*8);
      #pragma unroll
      for (int et=0; et<4; et++){
        s8v bv = *(const s8v*)(vbuf + (et*16+l15)*72 + ks*32 + lg*8);
        acc[et] = MFMA16(af, bv, acc[et], 0,0,0);
      }
    }
  }
  // outputs: ctxp[ch][b][h][d][e] bf16, Mp/Sp[ch][b][h][d]
  u16* cp = ctxp + (((size_t)ch*16 + b)*8 + h)*4096;
  #pragma unroll
  for (int et=0; et<4; et++)
    #pragma unroll
    for (int j=0;j<4;j++)
      cp[(w*16+lg*4+j)*64 + et*16+l15] = f2bf(acc[et][j]);
  if (l15==0){
    #pragma unroll
    for (int j=0;j<4;j++){
      int rg = (b*8+h)*64 + w*16 + lg*4 + j;
      Mp[ch*8192+rg]=M[j]; Sp[ch*8192+rg]=S[j];
    }
  }
}

// ---------------- kernel C: combine 8 chunk partials -> ctxT[b][h][e][d] bf16 ----------------
__global__ __launch_bounds__(256) void k_comb(const u16* __restrict__ ctxp, const float* __restrict__ Mp,
    const float* __restrict__ Sp, u16* __restrict__ ctxT){
  __shared__ float fs[8][64];
  __shared__ float iSs[64];
  const int bh = blockIdx.x, tid = threadIdx.x;   // 128 blocks
  if (tid < 64){
    float m[8];
    float Mg = -1e30f;
    #pragma unroll
    for (int ch=0;ch<8;ch++){ m[ch] = Mp[ch*8192 + bh*64 + tid]; Mg = fmaxf(Mg, m[ch]); }
    float Sg = 0.f;
    #pragma unroll
    for (int ch=0;ch<8;ch++){
      float fv = __expf(m[ch]-Mg);
      fs[ch][tid] = fv;
      Sg += Sp[ch*8192 + bh*64 + tid]*fv;
    }
    iSs[tid] = 1.0f / Sg;
  }
  __syncthreads();
  const int e = tid>>2, d0 = (tid&3)*16;
  u16* op = ctxT + (size_t)bh*4096 + e*64 + d0;
  #pragma unroll
  for (int i=0;i<16;i++){
    int d = d0+i;
    float v = 0.f;
    #pragma unroll
    for (int ch=0;ch<8;ch++)
      v += bf2f(ctxp[((size_t)(ch*128)+bh)*4096 + d*64 + e]) * fs[ch][d];
    op[i] = f2bf(v * iSs[d]);
  }
}

// ---------------- kernel D: q-GEMM + q-softmax + att + out-GEMM + bias + RMS ----------------
__global__ __launch_bounds__(256,2) void k_qout(const u16* __restrict__ xnT, const u16* __restrict__ wqkv,
    const u16* __restrict__ owb, const u16* __restrict__ ctxT,
    const float* __restrict__ ob, const float* __restrict__ onw, float* __restrict__ out){
  __shared__ u16 WQ[64*256];     // 32KB, row-swizzled
  __shared__ u16 OWs[256*64];    // 32KB, row-swizzled
  __shared__ u16 qa[4][16*80];   // per-wave transpose buffer
  __shared__ float obs[256], onws[256];
  const int tid = threadIdx.x;
  obs[tid]=ob[tid]; onws[tid]=onw[tid];
  __syncthreads();
  const int w=tid>>6, l=tid&63, l15=l&15, lg=l>>4;
  const int swl = (l15&7)<<4;
  const int blk=blockIdx.x, b=blk>>6, n0=(blk&63)*64 + w*16;
  const u16* xb = xnT + ((size_t)b*4096 + n0)*256;
  u16* qaw = qa[w];
  s8v ax[8];
  #pragma unroll
  for (int cs=0;cs<8;cs++) ax[cs] = *(const s8v*)(xb + (size_t)l15*256 + cs*32 + lg*8);
  f4v oacc[16];
  #pragma unroll
  for (int mt=0;mt<16;mt++) oacc[mt] = (f4v){0.f,0.f,0.f,0.f};

  for (int h=0; h<8; ++h){
    __syncthreads();
    {
      const u16* wqg = wqkv + (size_t)h*64*256;
      #pragma unroll
      for (int i=0;i<8;i++){
        int row = w*16 + i*2 + (l>>5);
        int colB = (l&31)*16;
        int scol = colB ^ ((row&7)<<4);
        gl_lds16(wqg + row*256 + (scol>>1), &WQ[(w*16 + i*2)*256]);
      }
    }
    {
      #pragma unroll
      for (int i=0;i<8;i++){
        int row = w*64 + i*8 + (l>>3);
        int colB = (l&7)*16;
        int scol = colB ^ ((row&7)<<4);
        gl_lds16(owb + (size_t)row*512 + h*64 + (scol>>1), &OWs[(w*64 + i*8)*64]);
      }
    }
    s8v bc[8];
    {
      const u16* cxb = ctxT + ((size_t)(b*8+h))*4096;
      #pragma unroll
      for (int ks=0; ks<2; ks++)
        #pragma unroll
        for (int et=0; et<4; et++)
          bc[ks*4+et] = *(const s8v*)(cxb + (et*16+l15)*64 + ks*32 + lg*8);
    }
    __syncthreads();
    f4v qacc[4];
    #pragma unroll
    for (int dt=0;dt<4;dt++) qacc[dt] = (f4v){0.f,0.f,0.f,0.f};
    #pragma unroll
    for (int dt=0; dt<4; dt++){
      #pragma unroll
      for (int cs=0; cs<8; cs++){
        s8v bw = *(const s8v*)&WQ[(dt*16+l15)*256 + ((((cs<<6)+(lg<<4)) ^ swl)>>1)];
        qacc[dt] = MFMA16(ax[cs], bw, qacc[dt], 0,0,0);
      }
    }
    #pragma unroll
    for (int j=0;j<4;j++){
      float m = fmaxf(fmaxf(qacc[0][j],qacc[1][j]),fmaxf(qacc[2][j],qacc[3][j]));
      #pragma unroll
      for (int d=1; d<16; d<<=1) m = fmaxf(m, __shfl_xor(m, d));
      float s = 0.f;
      #pragma unroll
      for (int dt=0;dt<4;dt++){ float e=__expf(qacc[dt][j]-m); qacc[dt][j]=e; s+=e; }
      #pragma unroll
      for (int d=1; d<16; d<<=1) s += __shfl_xor(s, d);
      float inv = 0.125f/s;
      #pragma unroll
      for (int dt=0;dt<4;dt++) qaw[(lg*4+j)*80 + dt*16+l15] = f2bf(qacc[dt][j]*inv);
    }
    f4v aacc[4];
    #pragma unroll
    for (int et=0;et<4;et++) aacc[et] = (f4v){0.f,0.f,0.f,0.f};
    #pragma unroll
    for (int ks=0; ks<2; ks++){
      s8v aq = *(const s8v*)&qaw[l15*80 + ks*32 + lg*8];
      #pragma unroll
      for (int et=0; et<4; et++)
        aacc[et] = MFMA16(aq, bc[ks*4+et], aacc[et], 0,0,0);
    }
    #pragma unroll
    for (int et=0;et<4;et++)
      #pragma unroll
      for (int j=0;j<4;j++)
        qaw[(lg*4+j)*80 + et*16+l15] = f2bf(aacc[et][j]);
    #pragma unroll
    for (int ks=0; ks<2; ks++){
      s8v ba = *(const s8v*)&qaw[l15*80 + ks*32 + lg*8];
      #pragma unroll
      for (int mt=0; mt<16; mt++){
        s8v aw = *(const s8v*)&OWs[(mt*16+l15)*64 + ((((ks<<6)+(lg<<4)) ^ swl)>>1)];
        oacc[mt] = MFMA16(aw, ba, oacc[mt], 0,0,0);
      }
    }
  }
  float ss = 0.f;
  #pragma unroll
  for (int mt=0;mt<16;mt++)
    #pragma unroll
    for (int j=0;j<4;j++){
      float v = oacc[mt][j] + obs[mt*16+lg*4+j];
      oacc[mt][j] = v;
      ss = fmaf(v,v,ss);
    }
  ss += __shfl_xor(ss, 16);
  ss += __shfl_xor(ss, 32);
  const float r = 16.0f / fmaxf(sqrtf(ss), 1e-12f);
  float* op = out + (size_t)b*(256*4096) + n0 + l15;
  #pragma unroll
  for (int mt=0;mt<16;mt++)
    #pragma unroll
    for (int j=0;j<4;j++){
      int cout = mt*16+lg*4+j;
      op[(size_t)cout*4096] = oacc[mt][j] * r * onws[cout];
    }
}

extern "C" void kernel_launch(void* const* d_in, const int* in_sizes, int n_in,
                              void* d_out, int out_size, void* d_ws, size_t ws_size,
                              hipStream_t stream){
  const float* x    = (const float*)d_in[0];
  const float* nw   = (const float*)d_in[1];
  const float* qkvw = (const float*)d_in[2];
  const float* ow   = (const float*)d_in[3];
  const float* ob   = (const float*)d_in[4];
  const float* onw  = (const float*)d_in[5];
  float* out = (float*)d_out;
  char* ws = (char*)d_ws;
  u16*   xnT  = (u16*)(ws);                    // 33,554,432 B
  u16*   wqkv = (u16*)(ws + 33554432);         //    786,432 B
  u16*   owb  = (u16*)(ws + 34340864);         //    262,144 B
  u16*   ctxT = (u16*)(ws + 34603008);         //  1,048,576 B
  u16*   ctxp = (u16*)(ws + 35651584);         //  8,388,608 B (8 chunks bf16)
  float* Mp   = (float*)(ws + 44040192);       //    262,144 B
  float* Sp   = (float*)(ws + 44302336);       //    262,144 B
  (void)in_sizes; (void)n_in; (void)out_size; (void)ws_size;

  k_prep <<<1024, 256, 0, stream>>>(x, nw, xnT);
  k_wconv<<<2048, 256, 0, stream>>>(qkvw, ow, wqkv, owb);
  k_kv   <<<1024, 256, 0, stream>>>(xnT, wqkv, ctxp, Mp, Sp);
  k_comb <<<128, 256, 0, stream>>>(ctxp, Mp, Sp, ctxT);
  k_qout <<<1024, 256, 0, stream>>>(xnT, wqkv, owb, ctxT, ob, onw, out);
}